// Round 2
// baseline (544.658 us; speedup 1.0000x reference)
//
#include <hip/hip_runtime.h>

#define NKV 8192
#define NB 64

typedef __attribute__((ext_vector_type(8))) short short8;
typedef __attribute__((ext_vector_type(8))) unsigned short ushort8;
typedef __attribute__((ext_vector_type(4))) float f32x4;

__device__ __forceinline__ float bf2f(unsigned short u) {
  return __uint_as_float(((unsigned int)u) << 16);
}
__device__ __forceinline__ unsigned short f2bf(float f) {
  unsigned int x = __float_as_uint(f);
  return (unsigned short)((x + 0x7fffu + ((x >> 16) & 1u)) >> 16);
}
__device__ __forceinline__ float sigm(float x) { return 1.f / (1.f + __expf(-x)); }

// ---------------------------------------------------------------------------
// K1: x_ln = LN(inputs); kv[tok][0:64] = (x_ln @ Wk)*0.25 (scale folded),
//     kv[tok][64:128] = x_ln @ Wv.  Stored bf16. MFMA 16x16x32 bf16.
// grid 512 x 256 threads; each wave: 256 tokens (16 tiles of 16).
// A frag: row=lane&15, k=(lane>>4)*8+i.  B frag: col=lane&15, same k.
// C frag: col=lane&15, row=(lane>>4)*4+reg  (m89-verified layout).
// ---------------------------------------------------------------------------
__global__ __launch_bounds__(256) void k_proj(
    const float* __restrict__ x, const float* __restrict__ gin,
    const float* __restrict__ bin, const float* __restrict__ Wk,
    const float* __restrict__ Wv, unsigned short* __restrict__ kv) {
  const int lane = threadIdx.x & 63;
  const int wave = threadIdx.x >> 6;
  const int half = lane >> 4, rlo = lane & 15;

  // B fragments for both K-halves and 8 output col-tiles (0-3 = k, 4-7 = v)
  short8 bfr[2][8];
#pragma unroll
  for (int kf = 0; kf < 2; ++kf)
#pragma unroll
    for (int ct = 0; ct < 8; ++ct) {
      const float* W = (ct < 4) ? Wk : Wv;
      int cc = (ct & 3) * 16 + rlo;
      short8 f;
#pragma unroll
      for (int i = 0; i < 8; ++i)
        f[i] = (short)f2bf(W[(kf * 32 + half * 8 + i) * 64 + cc]);
      bfr[kf][ct] = f;
    }
  float g0[8], g1[8], bb0[8], bb1[8];
#pragma unroll
  for (int i = 0; i < 8; ++i) {
    g0[i] = gin[half * 8 + i];      bb0[i] = bin[half * 8 + i];
    g1[i] = gin[32 + half * 8 + i]; bb1[i] = bin[32 + half * 8 + i];
  }
  long tok0 = ((long)blockIdx.x * 4 + wave) * 256;
  for (int tile = 0; tile < 16; ++tile) {
    long row = tok0 + tile * 16 + rlo;
    const f32x4* p4 = (const f32x4*)(x + row * 64);
    f32x4 u0 = p4[half * 2], u1 = p4[half * 2 + 1];
    f32x4 u2 = p4[8 + half * 2], u3 = p4[9 + half * 2];
    float s = 0.f, ss = 0.f;
#pragma unroll
    for (int i = 0; i < 4; ++i) {
      s += u0[i] + u1[i] + u2[i] + u3[i];
      ss = fmaf(u0[i], u0[i], fmaf(u1[i], u1[i], fmaf(u2[i], u2[i], fmaf(u3[i], u3[i], ss))));
    }
    // row r held by lanes r, r^16, r^32, r^48
    s += __shfl_xor(s, 16); ss += __shfl_xor(ss, 16);
    s += __shfl_xor(s, 32); ss += __shfl_xor(ss, 32);
    float m = s * 0.015625f;
    float var = ss * 0.015625f - m * m;
    float rs = rsqrtf(var + 1e-5f);
    short8 a0, a1;
#pragma unroll
    for (int i = 0; i < 4; ++i) {
      a0[i]     = (short)f2bf((u0[i] - m) * rs * g0[i]     + bb0[i]);
      a0[i + 4] = (short)f2bf((u1[i] - m) * rs * g0[i + 4] + bb0[i + 4]);
      a1[i]     = (short)f2bf((u2[i] - m) * rs * g1[i]     + bb1[i]);
      a1[i + 4] = (short)f2bf((u3[i] - m) * rs * g1[i + 4] + bb1[i + 4]);
    }
#pragma unroll
    for (int ct = 0; ct < 8; ++ct) {
      f32x4 acc = {0.f, 0.f, 0.f, 0.f};
      acc = __builtin_amdgcn_mfma_f32_16x16x32_bf16(a0, bfr[0][ct], acc, 0, 0, 0);
      acc = __builtin_amdgcn_mfma_f32_16x16x32_bf16(a1, bfr[1][ct], acc, 0, 0, 0);
      float sc = (ct < 4) ? 0.25f : 1.f;  // k-scale folded here
      int col = ct * 16 + rlo;
#pragma unroll
      for (int r = 0; r < 4; ++r) {
        long t = tok0 + tile * 16 + half * 4 + r;
        kv[t * 128 + col] = f2bf(acc[r] * sc);
      }
    }
  }
}

// ---------------------------------------------------------------------------
// K_prep: slots_buf = slots_in; q0 = LN(slots)@Wq * 0.25; zero S,W.
// grid B x 512 threads (one wave per slot row).
// ---------------------------------------------------------------------------
__global__ __launch_bounds__(512) void k_prep(
    const float* __restrict__ slots_in, const float* __restrict__ g_slot,
    const float* __restrict__ b_slot, const float* __restrict__ Wq,
    float* __restrict__ slots_buf, float* __restrict__ qbuf,
    float* __restrict__ Sg, float* __restrict__ Wg) {
  int b = blockIdx.x, tid = threadIdx.x;
  int s = tid >> 6, d = tid & 63;
  float x = slots_in[b * 512 + tid];
  slots_buf[b * 512 + tid] = x;
  float sum = x, sq = x * x;
#pragma unroll
  for (int msk = 1; msk < 64; msk <<= 1) { sum += __shfl_xor(sum, msk); sq += __shfl_xor(sq, msk); }
  float mean = sum * 0.015625f, var = sq * 0.015625f - mean * mean;
  float ln = (x - mean) * rsqrtf(var + 1e-5f) * g_slot[d] + b_slot[d];
  float acc = 0.f;
  for (int j = 0; j < 64; ++j) acc = fmaf(__shfl(ln, j), Wq[j * 64 + d], acc);
  acc *= 0.25f;
  qbuf[(b * 32 + (d >> 4) * 8 + s) * 16 + (d & 15)] = acc;
  if (tid < 32) Sg[b * 32 + tid] = 0.f;
  Wg[b * 512 + tid] = 0.f;
}

// ---------------------------------------------------------------------------
// K2: one streaming pass over kv. Per token: 32 logits (k.q), softmax over 32
// (lane-local hq, 5-step shfl_xor within 32-lane half), accumulate S and
// W[hq][16] in registers; block-reduce; atomicAdd to global S,W.
// Lane: hq = lane&31, token-half = lane>>5 (2 tokens per wave-iter).
// grid (B*32) x 256 threads; 256 tokens per block.
// ---------------------------------------------------------------------------
__global__ __launch_bounds__(256) void k_attn(
    const unsigned short* __restrict__ kv, const float* __restrict__ qbuf,
    float* __restrict__ Sg, float* __restrict__ Wg,
    float* __restrict__ vis, int last) {
  int b = blockIdx.x >> 5, chunk = blockIdx.x & 31;
  int lane = threadIdx.x & 63, wave = threadIdx.x >> 6;
  int hq = lane & 31, h = hq >> 3, qs = hq & 7;
  float qf[16];
  {
    const f32x4* qp = (const f32x4*)(qbuf + (b * 32 + hq) * 16);
#pragma unroll
    for (int i = 0; i < 4; ++i) {
      f32x4 t = qp[i];
      qf[i * 4 + 0] = t[0]; qf[i * 4 + 1] = t[1];
      qf[i * 4 + 2] = t[2]; qf[i * 4 + 3] = t[3];
    }
  }
  float Sl = 0.f, Wl[16];
#pragma unroll
  for (int d = 0; d < 16; ++d) Wl[d] = 0.f;
  int tb = chunk * 256 + wave * 64;
  for (int it = 0; it < 32; ++it) {
    int t = tb + it * 2 + (lane >> 5);
    long base = ((long)(b * NKV + t)) * 128;
    const ushort8* kp = (const ushort8*)(kv + base + h * 16);
    ushort8 k0 = kp[0], k1 = kp[1];
    const ushort8* vp = (const ushort8*)(kv + base + 64 + h * 16);
    ushort8 v0 = vp[0], v1 = vp[1];
    float logit = 0.f;
#pragma unroll
    for (int i = 0; i < 8; ++i) {
      logit = fmaf(bf2f(k0[i]), qf[i], logit);
      logit = fmaf(bf2f(k1[i]), qf[8 + i], logit);
    }
    float mx = logit;
#pragma unroll
    for (int msk = 1; msk <= 16; msk <<= 1) mx = fmaxf(mx, __shfl_xor(mx, msk));
    float e = __expf(logit - mx);
    float sum = e;
#pragma unroll
    for (int msk = 1; msk <= 16; msk <<= 1) sum += __shfl_xor(sum, msk);
    float attn = e * __builtin_amdgcn_rcpf(sum);
    if (last) {  // attn_vis = sum over heads of softmax (pre-EPS)
      float vh = attn + __shfl_xor(attn, 8);
      vh += __shfl_xor(vh, 16);
      if (hq < 8) vis[((long)(b * NKV + t)) * 8 + qs] = vh;
    }
    Sl += attn;
#pragma unroll
    for (int i = 0; i < 8; ++i) {
      Wl[i]     = fmaf(attn, bf2f(v0[i]), Wl[i]);
      Wl[8 + i] = fmaf(attn, bf2f(v1[i]), Wl[8 + i]);
    }
  }
  // combine the two token-halves of the wave
  Sl += __shfl_xor(Sl, 32);
#pragma unroll
  for (int d = 0; d < 16; ++d) Wl[d] += __shfl_xor(Wl[d], 32);
  __shared__ float redS[4][32];
  __shared__ float redW[4][32][16];
  if (lane < 32) {
    redS[wave][hq] = Sl;
#pragma unroll
    for (int d = 0; d < 16; ++d) redW[wave][hq][d] = Wl[d];
  }
  __syncthreads();
  int tid = threadIdx.x;
  if (tid < 32)
    atomicAdd(&Sg[b * 32 + tid],
              redS[0][tid] + redS[1][tid] + redS[2][tid] + redS[3][tid]);
#pragma unroll
  for (int r = 0; r < 2; ++r) {
    int idx = tid + r * 256;
    int hh = idx >> 4, dd = idx & 15;
    atomicAdd(&Wg[b * 512 + idx],
              redW[0][hh][dd] + redW[1][hh][dd] + redW[2][hh][dd] + redW[3][hh][dd]);
  }
}

// ---------------------------------------------------------------------------
// K3 (per batch, 512 thr = wave per slot): updates = W/(S + NKV*EPS);
// GRU; LN+MLP residual; write slots; q_next = LN(slots)@Wq*0.25; zero S,W.
// ---------------------------------------------------------------------------
__global__ __launch_bounds__(512) void k_update(
    float* __restrict__ Sg, float* __restrict__ Wg,
    float* __restrict__ slots_buf,
    const float* __restrict__ W_ih, const float* __restrict__ W_hh,
    const float* __restrict__ b_ih, const float* __restrict__ b_hh,
    const float* __restrict__ g_mlp, const float* __restrict__ b_mlp,
    const float* __restrict__ W1, const float* __restrict__ b1,
    const float* __restrict__ W2, const float* __restrict__ b2,
    const float* __restrict__ g_slot, const float* __restrict__ b_slot,
    const float* __restrict__ Wq, float* __restrict__ qbuf,
    float* __restrict__ out_slots, int compute_next, int write_out) {
  int b = blockIdx.x, tid = threadIdx.x;
  int s = tid >> 6, d = tid & 63;
  __shared__ float upd[8][64], hprev[8][64];
  __shared__ float gx[8][192], gh[8][192];
  __shared__ float lnm[8][64], h1s[8][128];
  float hp = slots_buf[b * 512 + tid];
  hprev[s][d] = hp;
  {
    int hh = d >> 4, dh = d & 15, hq2 = hh * 8 + s;
    float denom = Sg[b * 32 + hq2] + 8192.f * 1e-8f;
    upd[s][d] = Wg[(b * 32 + hq2) * 16 + dh] / denom;
  }
  __syncthreads();
#pragma unroll
  for (int w = 0; w < 3; ++w) {
    int idx = tid + w * 512;
    int ss = idx / 192, o = idx % 192;
    float ax = b_ih[o], ah = b_hh[o];
    for (int j = 0; j < 64; ++j) {
      ax = fmaf(upd[ss][j], W_ih[o * 64 + j], ax);
      ah = fmaf(hprev[ss][j], W_hh[o * 64 + j], ah);
    }
    gx[ss][o] = ax; gh[ss][o] = ah;
  }
  __syncthreads();
  float r = sigm(gx[s][d] + gh[s][d]);
  float z = sigm(gx[s][64 + d] + gh[s][64 + d]);
  float n = tanhf(gx[s][128 + d] + r * gh[s][128 + d]);
  float hn = (1.f - z) * n + z * hp;
  float sum = hn, sq = hn * hn;
#pragma unroll
  for (int msk = 1; msk < 64; msk <<= 1) { sum += __shfl_xor(sum, msk); sq += __shfl_xor(sq, msk); }
  float mean = sum * 0.015625f, var = sq * 0.015625f - mean * mean;
  float lnv = (hn - mean) * rsqrtf(var + 1e-5f) * g_mlp[d] + b_mlp[d];
  lnm[s][d] = lnv;
  __syncthreads();
#pragma unroll
  for (int w = 0; w < 2; ++w) {
    int idx = tid + w * 512;
    int ss = idx >> 7, c = idx & 127;
    float a = b1[c];
    for (int j = 0; j < 64; ++j) a = fmaf(lnm[ss][j], W1[j * 128 + c], a);
    h1s[ss][c] = fmaxf(a, 0.f);
  }
  __syncthreads();
  float a2 = b2[d];
  for (int c = 0; c < 128; ++c) a2 = fmaf(h1s[s][c], W2[c * 64 + d], a2);
  float outv = hn + a2;
  slots_buf[b * 512 + tid] = outv;
  if (write_out) out_slots[b * 512 + tid] = outv;
  if (compute_next) {
    float sum2 = outv, sq2 = outv * outv;
#pragma unroll
    for (int msk = 1; msk < 64; msk <<= 1) { sum2 += __shfl_xor(sum2, msk); sq2 += __shfl_xor(sq2, msk); }
    float mean2 = sum2 * 0.015625f, var2 = sq2 * 0.015625f - mean2 * mean2;
    float l2 = (outv - mean2) * rsqrtf(var2 + 1e-5f) * g_slot[d] + b_slot[d];
    float acc = 0.f;
    for (int j = 0; j < 64; ++j) acc = fmaf(__shfl(l2, j), Wq[j * 64 + d], acc);
    acc *= 0.25f;
    qbuf[(b * 32 + (d >> 4) * 8 + s) * 16 + (d & 15)] = acc;
    if (tid < 32) Sg[b * 32 + tid] = 0.f;
    Wg[b * 512 + tid] = 0.f;
  }
}

extern "C" void kernel_launch(void* const* d_in, const int* in_sizes, int n_in,
                              void* d_out, int out_size, void* d_ws, size_t ws_size,
                              hipStream_t stream) {
  const float* inputs    = (const float*)d_in[0];
  const float* slots     = (const float*)d_in[1];
  const float* ln_in_g   = (const float*)d_in[2];
  const float* ln_in_b   = (const float*)d_in[3];
  const float* ln_slot_g = (const float*)d_in[4];
  const float* ln_slot_b = (const float*)d_in[5];
  const float* ln_mlp_g  = (const float*)d_in[6];
  const float* ln_mlp_b  = (const float*)d_in[7];
  const float* Wq        = (const float*)d_in[8];
  const float* Wk        = (const float*)d_in[9];
  const float* Wv        = (const float*)d_in[10];
  const float* W_ih      = (const float*)d_in[11];
  const float* W_hh      = (const float*)d_in[12];
  const float* b_ih      = (const float*)d_in[13];
  const float* b_hh      = (const float*)d_in[14];
  const float* mlp_W1    = (const float*)d_in[15];
  const float* mlp_b1    = (const float*)d_in[16];
  const float* mlp_W2    = (const float*)d_in[17];
  const float* mlp_b2    = (const float*)d_in[18];

  float* out_slots = (float*)d_out;                 // [64*8*64]
  float* out_vis   = out_slots + 64 * 8 * 64;       // [64*8192*8]

  char* ws = (char*)d_ws;
  unsigned short* kv = (unsigned short*)ws;         // 64*8192*128 bf16 = 128 MiB
  size_t off = (size_t)64 * 8192 * 128 * 2;
  float* qbuf      = (float*)(ws + off); off += (size_t)64 * 32 * 16 * 4;
  float* Sg        = (float*)(ws + off); off += (size_t)64 * 32 * 4;
  float* Wg        = (float*)(ws + off); off += (size_t)64 * 512 * 4;
  float* slots_buf = (float*)(ws + off); off += (size_t)64 * 512 * 4;

  hipLaunchKernelGGL(k_proj, dim3(512), dim3(256), 0, stream,
                     inputs, ln_in_g, ln_in_b, Wk, Wv, kv);
  hipLaunchKernelGGL(k_prep, dim3(64), dim3(512), 0, stream,
                     slots, ln_slot_g, ln_slot_b, Wq, slots_buf, qbuf, Sg, Wg);
  for (int it = 0; it < 3; ++it) {
    hipLaunchKernelGGL(k_attn, dim3(64 * 32), dim3(256), 0, stream,
                       kv, qbuf, Sg, Wg, out_vis, it == 2 ? 1 : 0);
    hipLaunchKernelGGL(k_update, dim3(64), dim3(512), 0, stream,
                       Sg, Wg, slots_buf, W_ih, W_hh, b_ih, b_hh,
                       ln_mlp_g, ln_mlp_b, mlp_W1, mlp_b1, mlp_W2, mlp_b2,
                       ln_slot_g, ln_slot_b, Wq, qbuf, out_slots,
                       it < 2 ? 1 : 0, it == 2 ? 1 : 0);
  }
}

// Round 6
// 484.233 us; speedup vs baseline: 1.1248x; 1.1248x over previous
//
#include <hip/hip_runtime.h>

#define NKV 8192
#define NB 64

typedef __attribute__((ext_vector_type(8))) short short8;
typedef __attribute__((ext_vector_type(8))) unsigned short ushort8;
typedef __attribute__((ext_vector_type(4))) unsigned short usx4;
typedef __attribute__((ext_vector_type(4))) float f32x4;

__device__ __forceinline__ float bf2f(unsigned short u) {
  return __uint_as_float(((unsigned int)u) << 16);
}
__device__ __forceinline__ unsigned short f2bf(float f) {
  unsigned int x = __float_as_uint(f);
  return (unsigned short)((x + 0x7fffu + ((x >> 16) & 1u)) >> 16);
}
__device__ __forceinline__ float sigm(float x) { return 1.f / (1.f + __expf(-x)); }

// ---------------------------------------------------------------------------
// K0: convert Wk/Wv to bf16 MFMA fragments once.
// wf[idx=kf*512+ct*64+lane] = short8 A-fragment element (W^T chunk).
// ---------------------------------------------------------------------------
__global__ __launch_bounds__(256) void k_wprep(
    const float* __restrict__ Wk, const float* __restrict__ Wv,
    unsigned short* __restrict__ wf) {
  int idx = blockIdx.x * 256 + threadIdx.x;  // 0..1023
  int lane = idx & 63, ct = (idx >> 6) & 7, kf = idx >> 9;
  int half = lane >> 4, rlo = lane & 15;
  const float* W = (ct < 4) ? Wk : Wv;
  int cc = (ct & 3) * 16 + rlo;
  ushort8 pk;
#pragma unroll
  for (int i = 0; i < 8; ++i)
    pk[i] = f2bf(W[(kf * 32 + half * 8 + i) * 64 + cc]);
  *(ushort8*)(wf + (size_t)idx * 8) = pk;
}

// ---------------------------------------------------------------------------
// K1: x_ln = LN(inputs); kv[t][0:64]=(x_ln@Wk)*0.25, kv[t][64:128]=x_ln@Wv.
// MFMA with swapped operands: D = W^T · x^T so lane holds 4 CONSECUTIVE
// output dims of one token -> packed usx4 (8B) stores.
// A frag (weights): row=lane&15=odim, k=(lane>>4)*8+i.
// B frag (tokens):  col=lane&15=token, same k.
// C frag: col=lane&15=token, row=(lane>>4)*4+r = odim (m89 layout).
// grid 1024 x 256; each wave: 8 tiles of 16 tokens = 128 tokens.
// ---------------------------------------------------------------------------
__global__ __launch_bounds__(256) void k_proj(
    const float* __restrict__ x, const float* __restrict__ gin,
    const float* __restrict__ bin, const unsigned short* __restrict__ wf,
    unsigned short* __restrict__ kv) {
  const int lane = threadIdx.x & 63;
  const int wave = threadIdx.x >> 6;
  const int half = lane >> 4, rlo = lane & 15;

  short8 bfr[2][8];
  const ushort8* wf8 = (const ushort8*)wf;
#pragma unroll
  for (int kf = 0; kf < 2; ++kf)
#pragma unroll
    for (int ct = 0; ct < 8; ++ct)
      bfr[kf][ct] = (short8)wf8[(kf * 8 + ct) * 64 + lane];

  float g0[8], g1[8], bb0[8], bb1[8];
#pragma unroll
  for (int i = 0; i < 8; ++i) {
    g0[i] = gin[half * 8 + i];      bb0[i] = bin[half * 8 + i];
    g1[i] = gin[32 + half * 8 + i]; bb1[i] = bin[32 + half * 8 + i];
  }
  long tok0 = ((long)blockIdx.x * 4 + wave) * 128;
  for (int tile = 0; tile < 8; ++tile) {
    long row = tok0 + tile * 16 + rlo;
    const f32x4* p4 = (const f32x4*)(x + row * 64);
    f32x4 u0 = p4[half * 2], u1 = p4[half * 2 + 1];
    f32x4 u2 = p4[8 + half * 2], u3 = p4[9 + half * 2];
    float s = 0.f, ss = 0.f;
#pragma unroll
    for (int i = 0; i < 4; ++i) {
      s += u0[i] + u1[i] + u2[i] + u3[i];
      ss = fmaf(u0[i], u0[i], fmaf(u1[i], u1[i], fmaf(u2[i], u2[i], fmaf(u3[i], u3[i], ss))));
    }
    s += __shfl_xor(s, 16); ss += __shfl_xor(ss, 16);
    s += __shfl_xor(s, 32); ss += __shfl_xor(ss, 32);
    float m = s * 0.015625f;
    float var = ss * 0.015625f - m * m;
    float rs = rsqrtf(var + 1e-5f);
    short8 a0, a1;
#pragma unroll
    for (int i = 0; i < 4; ++i) {
      a0[i]     = (short)f2bf((u0[i] - m) * rs * g0[i]     + bb0[i]);
      a0[i + 4] = (short)f2bf((u1[i] - m) * rs * g0[i + 4] + bb0[i + 4]);
      a1[i]     = (short)f2bf((u2[i] - m) * rs * g1[i]     + bb1[i]);
      a1[i + 4] = (short)f2bf((u3[i] - m) * rs * g1[i + 4] + bb1[i + 4]);
    }
    long t = tok0 + tile * 16 + rlo;  // token owned by this lane (C col)
#pragma unroll
    for (int ct = 0; ct < 8; ++ct) {
      f32x4 acc = {0.f, 0.f, 0.f, 0.f};
      acc = __builtin_amdgcn_mfma_f32_16x16x32_bf16(bfr[0][ct], a0, acc, 0, 0, 0);
      acc = __builtin_amdgcn_mfma_f32_16x16x32_bf16(bfr[1][ct], a1, acc, 0, 0, 0);
      float sc = (ct < 4) ? 0.25f : 1.f;  // k head-scale folded
      usx4 pk;
#pragma unroll
      for (int r = 0; r < 4; ++r) pk[r] = f2bf(acc[r] * sc);
      *(usx4*)(kv + t * 128 + ct * 16 + half * 4) = pk;
    }
  }
}

// ---------------------------------------------------------------------------
// K_prep: one wave per (batch,slot). slots_buf=slots; q0=LN(slots)@Wq*0.25;
// zero S,W. grid 512 x 64.
// ---------------------------------------------------------------------------
__global__ __launch_bounds__(64) void k_prep(
    const float* __restrict__ slots_in, const float* __restrict__ g_slot,
    const float* __restrict__ b_slot, const float* __restrict__ Wq,
    float* __restrict__ slots_buf, float* __restrict__ qbuf,
    float* __restrict__ Sg, float* __restrict__ Wg) {
  int b = blockIdx.x >> 3, s = blockIdx.x & 7, d = threadIdx.x;
  __shared__ float l2_s[64];
  float x = slots_in[(b * 8 + s) * 64 + d];
  slots_buf[(b * 8 + s) * 64 + d] = x;
  float sum = x, sq = x * x;
#pragma unroll
  for (int msk = 1; msk < 64; msk <<= 1) { sum += __shfl_xor(sum, msk); sq += __shfl_xor(sq, msk); }
  float mean = sum * 0.015625f, var = sq * 0.015625f - mean * mean;
  float ln = (x - mean) * rsqrtf(var + 1e-5f) * g_slot[d] + b_slot[d];
  l2_s[d] = ln;
  __syncthreads();
  float acc = 0.f;
#pragma unroll 8
  for (int j = 0; j < 64; ++j) acc = fmaf(l2_s[j], Wq[j * 64 + d], acc);
  acc *= 0.25f;
  int hh = d >> 4, dh = d & 15, hq = hh * 8 + s;
  qbuf[(b * 32 + hq) * 16 + dh] = acc;
  if (d < 4) Sg[b * 32 + d * 8 + s] = 0.f;
  Wg[(b * 32 + hq) * 16 + dh] = 0.f;
}

// ---------------------------------------------------------------------------
// K2: streaming pass over kv. Per token: 32 logits, joint softmax over 32
// (no max-subtraction: |logit| ~ O(1) for LN'd data), accumulate S, W[hq][16]
// in registers; block-reduce; atomicAdd. grid (B*32) x 256.
// ---------------------------------------------------------------------------
__global__ __launch_bounds__(256) void k_attn(
    const unsigned short* __restrict__ kv, const float* __restrict__ qbuf,
    float* __restrict__ Sg, float* __restrict__ Wg,
    float* __restrict__ vis, int last) {
  int b = blockIdx.x >> 5, chunk = blockIdx.x & 31;
  int lane = threadIdx.x & 63, wave = threadIdx.x >> 6;
  int hq = lane & 31, h = hq >> 3, qs = hq & 7;
  float qf[16];
  {
    const f32x4* qp = (const f32x4*)(qbuf + (b * 32 + hq) * 16);
#pragma unroll
    for (int i = 0; i < 4; ++i) {
      f32x4 t = qp[i];
      qf[i * 4 + 0] = t[0]; qf[i * 4 + 1] = t[1];
      qf[i * 4 + 2] = t[2]; qf[i * 4 + 3] = t[3];
    }
  }
  float Sl = 0.f, Wl[16];
#pragma unroll
  for (int d = 0; d < 16; ++d) Wl[d] = 0.f;
  int tb = chunk * 256 + wave * 64;
  for (int it = 0; it < 32; ++it) {
    int t = tb + it * 2 + (lane >> 5);
    long base = ((long)(b * NKV + t)) * 128;
    const ushort8* kp = (const ushort8*)(kv + base + h * 16);
    ushort8 k0 = kp[0], k1 = kp[1];
    const ushort8* vp = (const ushort8*)(kv + base + 64 + h * 16);
    ushort8 v0 = vp[0], v1 = vp[1];
    float logit = 0.f;
#pragma unroll
    for (int i = 0; i < 8; ++i) {
      logit = fmaf(bf2f(k0[i]), qf[i], logit);
      logit = fmaf(bf2f(k1[i]), qf[8 + i], logit);
    }
    float e = __expf(logit);
    float sum = e;
#pragma unroll
    for (int msk = 1; msk <= 16; msk <<= 1) sum += __shfl_xor(sum, msk);
    float attn = e * __builtin_amdgcn_rcpf(sum);
    if (last) {  // attn_vis = per-token sum over heads (pre-EPS softmax)
      float vh = attn + __shfl_xor(attn, 8);
      vh += __shfl_xor(vh, 16);
      if (hq < 8) vis[((long)(b * NKV + t)) * 8 + qs] = vh;
    }
    Sl += attn;
#pragma unroll
    for (int i = 0; i < 8; ++i) {
      Wl[i]     = fmaf(attn, bf2f(v0[i]), Wl[i]);
      Wl[8 + i] = fmaf(attn, bf2f(v1[i]), Wl[8 + i]);
    }
  }
  Sl += __shfl_xor(Sl, 32);
#pragma unroll
  for (int d = 0; d < 16; ++d) Wl[d] += __shfl_xor(Wl[d], 32);
  __shared__ float redS[4][32];
  __shared__ float redW[4][32][16];
  if (lane < 32) {
    redS[wave][hq] = Sl;
#pragma unroll
    for (int d = 0; d < 16; ++d) redW[wave][hq][d] = Wl[d];
  }
  __syncthreads();
  int tid = threadIdx.x;
  if (tid < 32)
    atomicAdd(&Sg[b * 32 + tid],
              redS[0][tid] + redS[1][tid] + redS[2][tid] + redS[3][tid]);
#pragma unroll
  for (int r = 0; r < 2; ++r) {
    int idx = tid + r * 256;
    int hh = idx >> 4, dd = idx & 15;
    atomicAdd(&Wg[b * 512 + idx],
              redW[0][hh][dd] + redW[1][hh][dd] + redW[2][hh][dd] + redW[3][hh][dd]);
  }
}

// ---------------------------------------------------------------------------
// K3: one wave per (batch,slot). updates=W/(S+NKV*EPS); GRU; LN+MLP residual;
// next q; zero S,W. grid 512 x 64. Weight reads are per-j coalesced.
// ---------------------------------------------------------------------------
__global__ __launch_bounds__(64) void k_update(
    float* __restrict__ Sg, float* __restrict__ Wg,
    float* __restrict__ slots_buf,
    const float* __restrict__ W_ih, const float* __restrict__ W_hh,
    const float* __restrict__ b_ih, const float* __restrict__ b_hh,
    const float* __restrict__ g_mlp, const float* __restrict__ b_mlp,
    const float* __restrict__ W1, const float* __restrict__ b1,
    const float* __restrict__ W2, const float* __restrict__ b2,
    const float* __restrict__ g_slot, const float* __restrict__ b_slot,
    const float* __restrict__ Wq, float* __restrict__ qbuf,
    float* __restrict__ out_slots, int compute_next, int write_out) {
  int b = blockIdx.x >> 3, s = blockIdx.x & 7, d = threadIdx.x;
  __shared__ float upd_s[64], h_s[64], lnm_s[64], h1_s[128], l2_s[64];
  float hp = slots_buf[(b * 8 + s) * 64 + d];
  int hh = d >> 4, dh = d & 15, hq = hh * 8 + s;
  float denom = Sg[b * 32 + hq] + 8192.f * 1e-8f;
  float updv = Wg[(b * 32 + hq) * 16 + dh] / denom;
  upd_s[d] = updv; h_s[d] = hp;
  __syncthreads();
  float xr = b_ih[d], xz = b_ih[64 + d], xn = b_ih[128 + d];
  float hr = b_hh[d], hz = b_hh[64 + d], hv3 = b_hh[128 + d];
  const float* wi0 = W_ih + d * 64;
  const float* wi1 = W_ih + (64 + d) * 64;
  const float* wi2 = W_ih + (128 + d) * 64;
  const float* wh0 = W_hh + d * 64;
  const float* wh1 = W_hh + (64 + d) * 64;
  const float* wh2 = W_hh + (128 + d) * 64;
#pragma unroll 4
  for (int jj = 0; jj < 16; ++jj) {
    f32x4 u = *(const f32x4*)&upd_s[jj * 4];
    f32x4 hvv = *(const f32x4*)&h_s[jj * 4];
    f32x4 a0 = *(const f32x4*)&wi0[jj * 4];
    f32x4 a1 = *(const f32x4*)&wi1[jj * 4];
    f32x4 a2 = *(const f32x4*)&wi2[jj * 4];
    f32x4 c0 = *(const f32x4*)&wh0[jj * 4];
    f32x4 c1 = *(const f32x4*)&wh1[jj * 4];
    f32x4 c2 = *(const f32x4*)&wh2[jj * 4];
#pragma unroll
    for (int i = 0; i < 4; ++i) {
      xr = fmaf(u[i], a0[i], xr);  xz = fmaf(u[i], a1[i], xz);  xn = fmaf(u[i], a2[i], xn);
      hr = fmaf(hvv[i], c0[i], hr); hz = fmaf(hvv[i], c1[i], hz); hv3 = fmaf(hvv[i], c2[i], hv3);
    }
  }
  float r = sigm(xr + hr);
  float z = sigm(xz + hz);
  float n = tanhf(xn + r * hv3);
  float hn = (1.f - z) * n + z * hp;
  float sum = hn, sq = hn * hn;
#pragma unroll
  for (int msk = 1; msk < 64; msk <<= 1) { sum += __shfl_xor(sum, msk); sq += __shfl_xor(sq, msk); }
  float mean = sum * 0.015625f, var = sq * 0.015625f - mean * mean;
  float lnv = (hn - mean) * rsqrtf(var + 1e-5f) * g_mlp[d] + b_mlp[d];
  lnm_s[d] = lnv;
  __syncthreads();
  float a1a = b1[d], a1b = b1[64 + d];
#pragma unroll 8
  for (int j = 0; j < 64; ++j) {
    float lj = lnm_s[j];
    a1a = fmaf(lj, W1[j * 128 + d], a1a);
    a1b = fmaf(lj, W1[j * 128 + 64 + d], a1b);
  }
  h1_s[d] = fmaxf(a1a, 0.f); h1_s[64 + d] = fmaxf(a1b, 0.f);
  __syncthreads();
  float a2 = b2[d];
#pragma unroll 8
  for (int c = 0; c < 128; ++c) a2 = fmaf(h1_s[c], W2[c * 64 + d], a2);
  float outv = hn + a2;
  slots_buf[(b * 8 + s) * 64 + d] = outv;
  if (write_out) out_slots[(b * 8 + s) * 64 + d] = outv;
  if (compute_next) {
    float sum2 = outv, sq2 = outv * outv;
#pragma unroll
    for (int msk = 1; msk < 64; msk <<= 1) { sum2 += __shfl_xor(sum2, msk); sq2 += __shfl_xor(sq2, msk); }
    float mean2 = sum2 * 0.015625f, var2 = sq2 * 0.015625f - mean2 * mean2;
    float l2 = (outv - mean2) * rsqrtf(var2 + 1e-5f) * g_slot[d] + b_slot[d];
    l2_s[d] = l2;
    __syncthreads();
    float acc = 0.f;
#pragma unroll 8
    for (int j = 0; j < 64; ++j) acc = fmaf(l2_s[j], Wq[j * 64 + d], acc);
    acc *= 0.25f;
    qbuf[(b * 32 + hq) * 16 + dh] = acc;
    if (d < 4) Sg[b * 32 + d * 8 + s] = 0.f;
    Wg[(b * 32 + hq) * 16 + dh] = 0.f;
  }
}

extern "C" void kernel_launch(void* const* d_in, const int* in_sizes, int n_in,
                              void* d_out, int out_size, void* d_ws, size_t ws_size,
                              hipStream_t stream) {
  const float* inputs    = (const float*)d_in[0];
  const float* slots     = (const float*)d_in[1];
  const float* ln_in_g   = (const float*)d_in[2];
  const float* ln_in_b   = (const float*)d_in[3];
  const float* ln_slot_g = (const float*)d_in[4];
  const float* ln_slot_b = (const float*)d_in[5];
  const float* ln_mlp_g  = (const float*)d_in[6];
  const float* ln_mlp_b  = (const float*)d_in[7];
  const float* Wq        = (const float*)d_in[8];
  const float* Wk        = (const float*)d_in[9];
  const float* Wv        = (const float*)d_in[10];
  const float* W_ih      = (const float*)d_in[11];
  const float* W_hh      = (const float*)d_in[12];
  const float* b_ih      = (const float*)d_in[13];
  const float* b_hh      = (const float*)d_in[14];
  const float* mlp_W1    = (const float*)d_in[15];
  const float* mlp_b1    = (const float*)d_in[16];
  const float* mlp_W2    = (const float*)d_in[17];
  const float* mlp_b2    = (const float*)d_in[18];

  float* out_slots = (float*)d_out;                 // [64*8*64]
  float* out_vis   = out_slots + 64 * 8 * 64;       // [64*8192*8]

  char* ws = (char*)d_ws;
  unsigned short* kv = (unsigned short*)ws;         // 64*8192*128 bf16 = 128 MiB
  size_t off = (size_t)64 * 8192 * 128 * 2;
  float* qbuf      = (float*)(ws + off); off += (size_t)64 * 32 * 16 * 4;
  float* Sg        = (float*)(ws + off); off += (size_t)64 * 32 * 4;
  float* Wg        = (float*)(ws + off); off += (size_t)64 * 512 * 4;
  float* slots_buf = (float*)(ws + off); off += (size_t)64 * 512 * 4;
  unsigned short* wf = (unsigned short*)(ws + off); off += (size_t)1024 * 8 * 2;

  hipLaunchKernelGGL(k_wprep, dim3(4), dim3(256), 0, stream, Wk, Wv, wf);
  hipLaunchKernelGGL(k_proj, dim3(1024), dim3(256), 0, stream,
                     inputs, ln_in_g, ln_in_b, wf, kv);
  hipLaunchKernelGGL(k_prep, dim3(512), dim3(64), 0, stream,
                     slots, ln_slot_g, ln_slot_b, Wq, slots_buf, qbuf, Sg, Wg);
  for (int it = 0; it < 3; ++it) {
    hipLaunchKernelGGL(k_attn, dim3(64 * 32), dim3(256), 0, stream,
                       kv, qbuf, Sg, Wg, out_vis, it == 2 ? 1 : 0);
    hipLaunchKernelGGL(k_update, dim3(512), dim3(64), 0, stream,
                       Sg, Wg, slots_buf, W_ih, W_hh, b_ih, b_hh,
                       ln_mlp_g, ln_mlp_b, mlp_W1, mlp_b1, mlp_W2, mlp_b2,
                       ln_slot_g, ln_slot_b, Wq, qbuf, out_slots,
                       it < 2 ? 1 : 0, it == 2 ? 1 : 0);
  }
}

// Round 7
// 451.752 us; speedup vs baseline: 1.2057x; 1.0719x over previous
//
#include <hip/hip_runtime.h>

#define NKV 8192
#define NB 64

typedef __attribute__((ext_vector_type(8))) short short8;
typedef __attribute__((ext_vector_type(8))) unsigned short ushort8;
typedef __attribute__((ext_vector_type(4))) unsigned short usx4;
typedef __attribute__((ext_vector_type(4))) float f32x4;

__device__ __forceinline__ float bf2f(unsigned short u) {
  return __uint_as_float(((unsigned int)u) << 16);
}
__device__ __forceinline__ unsigned short f2bf(float f) {
  unsigned int x = __float_as_uint(f);
  return (unsigned short)((x + 0x7fffu + ((x >> 16) & 1u)) >> 16);
}
__device__ __forceinline__ float sigm(float x) { return 1.f / (1.f + __expf(-x)); }

// ---------------------------------------------------------------------------
// K0: convert Wk/Wv to bf16 MFMA fragments once (W^T chunks).
// ---------------------------------------------------------------------------
__global__ __launch_bounds__(256) void k_wprep(
    const float* __restrict__ Wk, const float* __restrict__ Wv,
    unsigned short* __restrict__ wf) {
  int idx = blockIdx.x * 256 + threadIdx.x;  // 0..1023
  int lane = idx & 63, ct = (idx >> 6) & 7, kf = idx >> 9;
  int half = lane >> 4, rlo = lane & 15;
  const float* W = (ct < 4) ? Wk : Wv;
  int cc = (ct & 3) * 16 + rlo;
  ushort8 pk;
#pragma unroll
  for (int i = 0; i < 8; ++i)
    pk[i] = f2bf(W[(kf * 32 + half * 8 + i) * 64 + cc]);
  *(ushort8*)(wf + (size_t)idx * 8) = pk;
}

// ---------------------------------------------------------------------------
// K1: LN + k/v projection, software-pipelined (prefetch next x-tile while
// computing current). grid 2048 x 256; 4 tiles of 16 tokens per wave.
// ---------------------------------------------------------------------------
__global__ __launch_bounds__(256) void k_proj(
    const float* __restrict__ x, const float* __restrict__ gin,
    const float* __restrict__ bin, const unsigned short* __restrict__ wf,
    unsigned short* __restrict__ kv) {
  const int lane = threadIdx.x & 63;
  const int wave = threadIdx.x >> 6;
  const int half = lane >> 4, rlo = lane & 15;
  const int NT = 4;

  short8 bfr[2][8];
  const ushort8* wf8 = (const ushort8*)wf;
#pragma unroll
  for (int kf = 0; kf < 2; ++kf)
#pragma unroll
    for (int ct = 0; ct < 8; ++ct)
      bfr[kf][ct] = (short8)wf8[(kf * 8 + ct) * 64 + lane];

  float g0[8], g1[8], bb0[8], bb1[8];
#pragma unroll
  for (int i = 0; i < 8; ++i) {
    g0[i] = gin[half * 8 + i];      bb0[i] = bin[half * 8 + i];
    g1[i] = gin[32 + half * 8 + i]; bb1[i] = bin[32 + half * 8 + i];
  }
  long tok0 = ((long)blockIdx.x * 4 + wave) * (NT * 16);
  // prefetch tile 0
  const f32x4* p4 = (const f32x4*)(x + (tok0 + rlo) * 64);
  f32x4 cu0 = p4[half * 2], cu1 = p4[half * 2 + 1];
  f32x4 cu2 = p4[8 + half * 2], cu3 = p4[9 + half * 2];
#pragma unroll
  for (int tile = 0; tile < NT; ++tile) {
    // issue next tile's loads first (retire under this tile's compute)
    int tn = (tile < NT - 1) ? tile + 1 : tile;
    const f32x4* pn = (const f32x4*)(x + (tok0 + tn * 16 + rlo) * 64);
    f32x4 nu0 = pn[half * 2], nu1 = pn[half * 2 + 1];
    f32x4 nu2 = pn[8 + half * 2], nu3 = pn[9 + half * 2];

    float s = 0.f, ss = 0.f;
#pragma unroll
    for (int i = 0; i < 4; ++i) {
      s += cu0[i] + cu1[i] + cu2[i] + cu3[i];
      ss = fmaf(cu0[i], cu0[i], fmaf(cu1[i], cu1[i], fmaf(cu2[i], cu2[i], fmaf(cu3[i], cu3[i], ss))));
    }
    // row r held by lanes r, r^16, r^32, r^48
    s += __shfl_xor(s, 16); ss += __shfl_xor(ss, 16);
    s += __shfl_xor(s, 32); ss += __shfl_xor(ss, 32);
    float m = s * 0.015625f;
    float var = ss * 0.015625f - m * m;
    float rs = rsqrtf(var + 1e-5f);
    short8 a0, a1;
#pragma unroll
    for (int i = 0; i < 4; ++i) {
      a0[i]     = (short)f2bf((cu0[i] - m) * rs * g0[i]     + bb0[i]);
      a0[i + 4] = (short)f2bf((cu1[i] - m) * rs * g0[i + 4] + bb0[i + 4]);
      a1[i]     = (short)f2bf((cu2[i] - m) * rs * g1[i]     + bb1[i]);
      a1[i + 4] = (short)f2bf((cu3[i] - m) * rs * g1[i + 4] + bb1[i + 4]);
    }
    long t = tok0 + tile * 16 + rlo;  // token owned by this lane (C col)
#pragma unroll
    for (int ct = 0; ct < 8; ++ct) {
      f32x4 acc = {0.f, 0.f, 0.f, 0.f};
      acc = __builtin_amdgcn_mfma_f32_16x16x32_bf16(bfr[0][ct], a0, acc, 0, 0, 0);
      acc = __builtin_amdgcn_mfma_f32_16x16x32_bf16(bfr[1][ct], a1, acc, 0, 0, 0);
      float sc = (ct < 4) ? 0.25f : 1.f;  // k head-scale folded
      usx4 pk;
#pragma unroll
      for (int r = 0; r < 4; ++r) pk[r] = f2bf(acc[r] * sc);
      *(usx4*)(kv + t * 128 + ct * 16 + half * 4) = pk;
    }
    cu0 = nu0; cu1 = nu1; cu2 = nu2; cu3 = nu3;
  }
}

// ---------------------------------------------------------------------------
// K_prep: one wave per (batch,slot). grid 512 x 64.
// ---------------------------------------------------------------------------
__global__ __launch_bounds__(64) void k_prep(
    const float* __restrict__ slots_in, const float* __restrict__ g_slot,
    const float* __restrict__ b_slot, const float* __restrict__ Wq,
    float* __restrict__ slots_buf, float* __restrict__ qbuf,
    float* __restrict__ Sg, float* __restrict__ Wg) {
  int b = blockIdx.x >> 3, s = blockIdx.x & 7, d = threadIdx.x;
  __shared__ float l2_s[64];
  float x = slots_in[(b * 8 + s) * 64 + d];
  slots_buf[(b * 8 + s) * 64 + d] = x;
  float sum = x, sq = x * x;
#pragma unroll
  for (int msk = 1; msk < 64; msk <<= 1) { sum += __shfl_xor(sum, msk); sq += __shfl_xor(sq, msk); }
  float mean = sum * 0.015625f, var = sq * 0.015625f - mean * mean;
  float ln = (x - mean) * rsqrtf(var + 1e-5f) * g_slot[d] + b_slot[d];
  l2_s[d] = ln;
  __syncthreads();
  float acc = 0.f;
#pragma unroll 8
  for (int j = 0; j < 64; ++j) acc = fmaf(l2_s[j], Wq[j * 64 + d], acc);
  acc *= 0.25f;
  int hh = d >> 4, dh = d & 15, hq = hh * 8 + s;
  qbuf[(b * 32 + hq) * 16 + dh] = acc;
  if (d < 4) Sg[b * 32 + d * 8 + s] = 0.f;
  Wg[(b * 32 + hq) * 16 + dh] = 0.f;
}

// ---------------------------------------------------------------------------
// K2 (templated per iteration for profiling): streaming pass over kv with
// register double-buffer prefetch of next token-pair's k/v.
// grid (B*32) x 256; 256 tokens per block, 64 per wave.
// ---------------------------------------------------------------------------
template <int IT>
__global__ __launch_bounds__(256) void k_attn(
    const unsigned short* __restrict__ kv, const float* __restrict__ qbuf,
    float* __restrict__ Sg, float* __restrict__ Wg,
    float* __restrict__ vis) {
  constexpr bool last = (IT == 2);
  int b = blockIdx.x >> 5, chunk = blockIdx.x & 31;
  int lane = threadIdx.x & 63, wave = threadIdx.x >> 6;
  int hq = lane & 31, h = hq >> 3, qs = hq & 7;
  float qf[16];
  {
    const f32x4* qp = (const f32x4*)(qbuf + (b * 32 + hq) * 16);
#pragma unroll
    for (int i = 0; i < 4; ++i) {
      f32x4 t = qp[i];
      qf[i * 4 + 0] = t[0]; qf[i * 4 + 1] = t[1];
      qf[i * 4 + 2] = t[2]; qf[i * 4 + 3] = t[3];
    }
  }
  float Sl = 0.f, Wl[16];
#pragma unroll
  for (int d = 0; d < 16; ++d) Wl[d] = 0.f;
  int tb = chunk * 256 + wave * 64 + (lane >> 5);
  // prefetch it=0
  long base = ((long)(b * NKV + tb)) * 128;
  const ushort8* kp = (const ushort8*)(kv + base + h * 16);
  const ushort8* vp = (const ushort8*)(kv + base + 64 + h * 16);
  ushort8 ck0 = kp[0], ck1 = kp[1], cv0 = vp[0], cv1 = vp[1];
  for (int it = 0; it < 32; ++it) {
    int t = tb + it * 2;
    // issue next pair's loads (clamped on last iter; redundant but in-bounds)
    int itn = (it < 31) ? it + 1 : it;
    long nbase = ((long)(b * NKV + tb + itn * 2)) * 128;
    const ushort8* nkp = (const ushort8*)(kv + nbase + h * 16);
    const ushort8* nvp = (const ushort8*)(kv + nbase + 64 + h * 16);
    ushort8 nk0 = nkp[0], nk1 = nkp[1], nv0 = nvp[0], nv1 = nvp[1];

    float logit = 0.f;
#pragma unroll
    for (int i = 0; i < 8; ++i) {
      logit = fmaf(bf2f(ck0[i]), qf[i], logit);
      logit = fmaf(bf2f(ck1[i]), qf[8 + i], logit);
    }
    float e = __expf(logit);
    float sum = e;
#pragma unroll
    for (int msk = 1; msk <= 16; msk <<= 1) sum += __shfl_xor(sum, msk);
    float attn = e * __builtin_amdgcn_rcpf(sum);
    if (last) {  // attn_vis = per-token sum over heads (pre-EPS softmax)
      float vh = attn + __shfl_xor(attn, 8);
      vh += __shfl_xor(vh, 16);
      if (hq < 8) vis[((long)(b * NKV + t)) * 8 + qs] = vh;
    }
    Sl += attn;
#pragma unroll
    for (int i = 0; i < 8; ++i) {
      Wl[i]     = fmaf(attn, bf2f(cv0[i]), Wl[i]);
      Wl[8 + i] = fmaf(attn, bf2f(cv1[i]), Wl[8 + i]);
    }
    ck0 = nk0; ck1 = nk1; cv0 = nv0; cv1 = nv1;
  }
  Sl += __shfl_xor(Sl, 32);
#pragma unroll
  for (int d = 0; d < 16; ++d) Wl[d] += __shfl_xor(Wl[d], 32);
  __shared__ float redS[4][32];
  __shared__ float redW[4][32][16];
  if (lane < 32) {
    redS[wave][hq] = Sl;
#pragma unroll
    for (int d = 0; d < 16; ++d) redW[wave][hq][d] = Wl[d];
  }
  __syncthreads();
  int tid = threadIdx.x;
  if (tid < 32)
    atomicAdd(&Sg[b * 32 + tid],
              redS[0][tid] + redS[1][tid] + redS[2][tid] + redS[3][tid]);
#pragma unroll
  for (int r = 0; r < 2; ++r) {
    int idx = tid + r * 256;
    int hh = idx >> 4, dd = idx & 15;
    atomicAdd(&Wg[b * 512 + idx],
              redW[0][hh][dd] + redW[1][hh][dd] + redW[2][hh][dd] + redW[3][hh][dd]);
  }
}

// ---------------------------------------------------------------------------
// K3 (templated per iteration): one wave per (batch,slot). grid 512 x 64.
// ---------------------------------------------------------------------------
template <int IT>
__global__ __launch_bounds__(64) void k_update(
    float* __restrict__ Sg, float* __restrict__ Wg,
    float* __restrict__ slots_buf,
    const float* __restrict__ W_ih, const float* __restrict__ W_hh,
    const float* __restrict__ b_ih, const float* __restrict__ b_hh,
    const float* __restrict__ g_mlp, const float* __restrict__ b_mlp,
    const float* __restrict__ W1, const float* __restrict__ b1,
    const float* __restrict__ W2, const float* __restrict__ b2,
    const float* __restrict__ g_slot, const float* __restrict__ b_slot,
    const float* __restrict__ Wq, float* __restrict__ qbuf,
    float* __restrict__ out_slots) {
  constexpr int compute_next = (IT < 2);
  constexpr int write_out = (IT == 2);
  int b = blockIdx.x >> 3, s = blockIdx.x & 7, d = threadIdx.x;
  __shared__ float upd_s[64], h_s[64], lnm_s[64], h1_s[128], l2_s[64];
  float hp = slots_buf[(b * 8 + s) * 64 + d];
  int hh = d >> 4, dh = d & 15, hq = hh * 8 + s;
  float denom = Sg[b * 32 + hq] + 8192.f * 1e-8f;
  float updv = Wg[(b * 32 + hq) * 16 + dh] / denom;
  upd_s[d] = updv; h_s[d] = hp;
  __syncthreads();
  float xr = b_ih[d], xz = b_ih[64 + d], xn = b_ih[128 + d];
  float hr = b_hh[d], hz = b_hh[64 + d], hv3 = b_hh[128 + d];
  const float* wi0 = W_ih + d * 64;
  const float* wi1 = W_ih + (64 + d) * 64;
  const float* wi2 = W_ih + (128 + d) * 64;
  const float* wh0 = W_hh + d * 64;
  const float* wh1 = W_hh + (64 + d) * 64;
  const float* wh2 = W_hh + (128 + d) * 64;
#pragma unroll 4
  for (int jj = 0; jj < 16; ++jj) {
    f32x4 u = *(const f32x4*)&upd_s[jj * 4];
    f32x4 hvv = *(const f32x4*)&h_s[jj * 4];
    f32x4 a0 = *(const f32x4*)&wi0[jj * 4];
    f32x4 a1 = *(const f32x4*)&wi1[jj * 4];
    f32x4 a2 = *(const f32x4*)&wi2[jj * 4];
    f32x4 c0 = *(const f32x4*)&wh0[jj * 4];
    f32x4 c1 = *(const f32x4*)&wh1[jj * 4];
    f32x4 c2 = *(const f32x4*)&wh2[jj * 4];
#pragma unroll
    for (int i = 0; i < 4; ++i) {
      xr = fmaf(u[i], a0[i], xr);  xz = fmaf(u[i], a1[i], xz);  xn = fmaf(u[i], a2[i], xn);
      hr = fmaf(hvv[i], c0[i], hr); hz = fmaf(hvv[i], c1[i], hz); hv3 = fmaf(hvv[i], c2[i], hv3);
    }
  }
  float r = sigm(xr + hr);
  float z = sigm(xz + hz);
  float n = tanhf(xn + r * hv3);
  float hn = (1.f - z) * n + z * hp;
  float sum = hn, sq = hn * hn;
#pragma unroll
  for (int msk = 1; msk < 64; msk <<= 1) { sum += __shfl_xor(sum, msk); sq += __shfl_xor(sq, msk); }
  float mean = sum * 0.015625f, var = sq * 0.015625f - mean * mean;
  float lnv = (hn - mean) * rsqrtf(var + 1e-5f) * g_mlp[d] + b_mlp[d];
  lnm_s[d] = lnv;
  __syncthreads();
  float a1a = b1[d], a1b = b1[64 + d];
#pragma unroll 8
  for (int j = 0; j < 64; ++j) {
    float lj = lnm_s[j];
    a1a = fmaf(lj, W1[j * 128 + d], a1a);
    a1b = fmaf(lj, W1[j * 128 + 64 + d], a1b);
  }
  h1_s[d] = fmaxf(a1a, 0.f); h1_s[64 + d] = fmaxf(a1b, 0.f);
  __syncthreads();
  float a2 = b2[d];
#pragma unroll 8
  for (int c = 0; c < 128; ++c) a2 = fmaf(h1_s[c], W2[c * 64 + d], a2);
  float outv = hn + a2;
  slots_buf[(b * 8 + s) * 64 + d] = outv;
  if (write_out) out_slots[(b * 8 + s) * 64 + d] = outv;
  if (compute_next) {
    float sum2 = outv, sq2 = outv * outv;
#pragma unroll
    for (int msk = 1; msk < 64; msk <<= 1) { sum2 += __shfl_xor(sum2, msk); sq2 += __shfl_xor(sq2, msk); }
    float mean2 = sum2 * 0.015625f, var2 = sq2 * 0.015625f - mean2 * mean2;
    float l2 = (outv - mean2) * rsqrtf(var2 + 1e-5f) * g_slot[d] + b_slot[d];
    l2_s[d] = l2;
    __syncthreads();
    float acc = 0.f;
#pragma unroll 8
    for (int j = 0; j < 64; ++j) acc = fmaf(l2_s[j], Wq[j * 64 + d], acc);
    acc *= 0.25f;
    qbuf[(b * 32 + hq) * 16 + dh] = acc;
    if (d < 4) Sg[b * 32 + d * 8 + s] = 0.f;
    Wg[(b * 32 + hq) * 16 + dh] = 0.f;
  }
}

extern "C" void kernel_launch(void* const* d_in, const int* in_sizes, int n_in,
                              void* d_out, int out_size, void* d_ws, size_t ws_size,
                              hipStream_t stream) {
  const float* inputs    = (const float*)d_in[0];
  const float* slots     = (const float*)d_in[1];
  const float* ln_in_g   = (const float*)d_in[2];
  const float* ln_in_b   = (const float*)d_in[3];
  const float* ln_slot_g = (const float*)d_in[4];
  const float* ln_slot_b = (const float*)d_in[5];
  const float* ln_mlp_g  = (const float*)d_in[6];
  const float* ln_mlp_b  = (const float*)d_in[7];
  const float* Wq        = (const float*)d_in[8];
  const float* Wk        = (const float*)d_in[9];
  const float* Wv        = (const float*)d_in[10];
  const float* W_ih      = (const float*)d_in[11];
  const float* W_hh      = (const float*)d_in[12];
  const float* b_ih      = (const float*)d_in[13];
  const float* b_hh      = (const float*)d_in[14];
  const float* mlp_W1    = (const float*)d_in[15];
  const float* mlp_b1    = (const float*)d_in[16];
  const float* mlp_W2    = (const float*)d_in[17];
  const float* mlp_b2    = (const float*)d_in[18];

  float* out_slots = (float*)d_out;                 // [64*8*64]
  float* out_vis   = out_slots + 64 * 8 * 64;       // [64*8192*8]

  char* ws = (char*)d_ws;
  unsigned short* kv = (unsigned short*)ws;         // 64*8192*128 bf16 = 128 MiB
  size_t off = (size_t)64 * 8192 * 128 * 2;
  float* qbuf      = (float*)(ws + off); off += (size_t)64 * 32 * 16 * 4;
  float* Sg        = (float*)(ws + off); off += (size_t)64 * 32 * 4;
  float* Wg        = (float*)(ws + off); off += (size_t)64 * 512 * 4;
  float* slots_buf = (float*)(ws + off); off += (size_t)64 * 512 * 4;
  unsigned short* wf = (unsigned short*)(ws + off); off += (size_t)1024 * 8 * 2;

  hipLaunchKernelGGL(k_wprep, dim3(4), dim3(256), 0, stream, Wk, Wv, wf);
  hipLaunchKernelGGL(k_proj, dim3(2048), dim3(256), 0, stream,
                     inputs, ln_in_g, ln_in_b, wf, kv);
  hipLaunchKernelGGL(k_prep, dim3(512), dim3(64), 0, stream,
                     slots, ln_slot_g, ln_slot_b, Wq, slots_buf, qbuf, Sg, Wg);

  hipLaunchKernelGGL((k_attn<0>), dim3(64 * 32), dim3(256), 0, stream,
                     kv, qbuf, Sg, Wg, out_vis);
  hipLaunchKernelGGL((k_update<0>), dim3(512), dim3(64), 0, stream,
                     Sg, Wg, slots_buf, W_ih, W_hh, b_ih, b_hh,
                     ln_mlp_g, ln_mlp_b, mlp_W1, mlp_b1, mlp_W2, mlp_b2,
                     ln_slot_g, ln_slot_b, Wq, qbuf, out_slots);
  hipLaunchKernelGGL((k_attn<1>), dim3(64 * 32), dim3(256), 0, stream,
                     kv, qbuf, Sg, Wg, out_vis);
  hipLaunchKernelGGL((k_update<1>), dim3(512), dim3(64), 0, stream,
                     Sg, Wg, slots_buf, W_ih, W_hh, b_ih, b_hh,
                     ln_mlp_g, ln_mlp_b, mlp_W1, mlp_b1, mlp_W2, mlp_b2,
                     ln_slot_g, ln_slot_b, Wq, qbuf, out_slots);
  hipLaunchKernelGGL((k_attn<2>), dim3(64 * 32), dim3(256), 0, stream,
                     kv, qbuf, Sg, Wg, out_vis);
  hipLaunchKernelGGL((k_update<2>), dim3(512), dim3(64), 0, stream,
                     Sg, Wg, slots_buf, W_ih, W_hh, b_ih, b_hh,
                     ln_mlp_g, ln_mlp_b, mlp_W1, mlp_b1, mlp_W2, mlp_b2,
                     ln_slot_g, ln_slot_b, Wq, qbuf, out_slots);
}